// Round 2
// baseline (11951.905 us; speedup 1.0000x reference)
//
#include <hip/hip_runtime.h>

#define B_   64
#define T_   1024
#define IN_  64
#define H_   512
#define OUT_ 64
#define BH   (64*512)
#define NWG  130

typedef _Float16 f16;
typedef _Float16 half8 __attribute__((ext_vector_type(8)));
typedef float    floatx4 __attribute__((ext_vector_type(4)));
typedef unsigned int u32;

#define MFMA16(a,b,c) __builtin_amdgcn_mfma_f32_16x16x32_f16((a),(b),(c),0,0,0)

__device__ __forceinline__ float sigmoidf_(float x) {
    return 1.0f / (1.0f + __expf(-x));
}
__device__ __forceinline__ float tanhf_(float x) {
    float ax = fabsf(x);
    float e  = __expf(-2.0f * ax);
    float t  = (1.0f - e) / (1.0f + e);
    return x >= 0.0f ? t : -t;
}

// ---------------- prep kernels (weights -> fp16 fragment-linear) ----------------
// W1p flat = (((g*32 + jt)*18 + kt)*64 + lane)*8 + j
__global__ void pack_w1(const float* __restrict__ Wih, const float* __restrict__ Whh,
                        f16* __restrict__ Wp) {
    int idx = blockIdx.x * 256 + threadIdx.x;
    if (idx >= 4*32*18*512) return;
    int j    = idx & 7;
    int lane = (idx >> 3) & 63;
    int kt   = (idx >> 9) % 18;
    int r    = (idx >> 9) / 18;
    int jt   = r & 31;
    int g    = r >> 5;
    int n = g*512 + jt*16 + (lane & 15);
    int k = kt*32 + (lane >> 4)*8 + j;
    float v = (k < 64) ? Wih[n*64 + k] : Whh[n*512 + (k - 64)];
    Wp[idx] = (f16)v;
}

__global__ void pack_w2(const float* __restrict__ Wih, const float* __restrict__ Whh,
                        f16* __restrict__ Wp) {
    int idx = blockIdx.x * 256 + threadIdx.x;
    if (idx >= 4*32*32*512) return;
    int j    = idx & 7;
    int lane = (idx >> 3) & 63;
    int kt   = (idx >> 9) & 31;
    int r    = idx >> 14;
    int jt   = r & 31;
    int g    = r >> 5;
    int n = g*512 + jt*16 + (lane & 15);
    int k = kt*32 + (lane >> 4)*8 + j;
    float v = (k < 512) ? Wih[n*512 + k] : Whh[n*512 + (k - 512)];
    Wp[idx] = (f16)v;
}

__global__ void pack_wo(const float* __restrict__ Wout, f16* __restrict__ Wp) {
    int idx = blockIdx.x * 256 + threadIdx.x;
    if (idx >= 4*16*512) return;
    int j    = idx & 7;
    int lane = (idx >> 3) & 63;
    int kt   = (idx >> 9) & 15;
    int nt   = idx >> 13;
    int n = nt*16 + (lane & 15);
    int k = kt*32 + (lane >> 4)*8 + j;
    Wp[idx] = (f16)Wout[n*512 + k];
}

__global__ void bias_sum(const float* __restrict__ a1, const float* __restrict__ b1,
                         const float* __restrict__ a2, const float* __restrict__ b2,
                         float* __restrict__ s1, float* __restrict__ s2) {
    int i = blockIdx.x * 256 + threadIdx.x;
    if (i >= 2048) return;
    s1[i] = a1[i] + b1[i];
    s2[i] = a2[i] + b2[i];
}

// ---------------- grid barrier ----------------
__device__ __forceinline__ void gridbar(u32* cnt, int p) {
    __syncthreads();
    if (threadIdx.x == 0) {
        __threadfence();   // flush this WG's h-writes to device scope (wbl2)
        __hip_atomic_fetch_add(cnt, 1u, __ATOMIC_RELAXED, __HIP_MEMORY_SCOPE_AGENT);
        const u32 target = (u32)(p + 1) * NWG;
        while (__hip_atomic_load(cnt, __ATOMIC_RELAXED, __HIP_MEMORY_SCOPE_AGENT) < target)
            __builtin_amdgcn_s_sleep(1);
        __threadfence();   // invalidate caches before reading others' h
    }
    __syncthreads();
}

// ---------------- persistent kernel ----------------
// 130 WGs x 512 threads, all phases inside one launch, weights in VGPRs.
// WG 0..63:   layer1, jt = wg&31, batch-half = wg>>5.  waves: gp=w&1, kh=(w>>1)&1, mq=w>>2
// WG 64..127: layer2, v=wg-64: jt=v&31, bhalf=v>>5.    waves: gp=w&1, kq=w>>1 (4-way K split)
// WG 128..129: head, bhalf = wg-128.                   waves: nt=w&3, kh=w>>2
// LDS: STG_X @0 (8KB, L1 x fp32), STG_H @8192 (32KB), RA @40960 (8KB), RB @49152 (8KB), CC @57344 (2KB)
__global__ __launch_bounds__(512, 1) void lstm_persist(
    const float* __restrict__ x,
    const f16*  __restrict__ W1p,
    const f16*  __restrict__ W2p,
    const f16*  __restrict__ Wop,
    const float* __restrict__ bs1,
    const float* __restrict__ bs2,
    const float* __restrict__ bout,
    f16*  __restrict__ h1buf,
    f16*  __restrict__ h2buf,
    float* __restrict__ y,
    u32*  __restrict__ cnt)
{
    __shared__ __align__(16) char smem[59392];
    float* RA = (float*)(smem + 40960);
    float* RB = (float*)(smem + 49152);
    float* CC = (float*)(smem + 57344);

    const int wg   = blockIdx.x;
    const int tid  = threadIdx.x;
    const int lane = tid & 63;
    const int w    = tid >> 6;
    const int col  = lane & 15;
    const int quad = lane >> 4;

    if (wg < 64) {
        // ================= layer 1 =================
        const int jt = wg & 31, bhalf = wg >> 5;
        const int gp = w & 1, kh = (w >> 1) & 1, mq = w >> 2;
        half8 wr[2][9];
        #pragma unroll
        for (int gi = 0; gi < 2; ++gi)
            #pragma unroll
            for (int k = 0; k < 9; ++k) {
                const int g = gp*2 + gi, kt = kh*9 + k;
                wr[gi][k] = *(const half8*)(W1p + ((size_t)((g*32 + jt)*18 + kt)*64 + lane)*8);
            }
        float bsr[4];
        #pragma unroll
        for (int g = 0; g < 4; ++g) bsr[g] = bs1[g*512 + jt*16 + (tid & 15)];
        CC[tid] = 0.f;

        const int lb_a = mq*16 + col;
        const int sw_a = lb_a & 7;

        for (int p = 0; p < T_ + 2; ++p) {
            if (p < T_) {
                const int t = p;
                const int sR = (p + 1) & 1, sW = p & 1;
                {   // stage x_t (fp32, 8KB, swizzled 16B granules)
                    const int lb = tid >> 4, kc4 = tid & 15;
                    const float* src = x + ((size_t)(bhalf*32 + lb)*T_ + t)*(size_t)IN_ + ((kc4 ^ (lb & 7)) * 4);
                    *(float4*)(smem + tid*16) = *(const float4*)src;
                }
                #pragma unroll
                for (int i = 0; i < 4; ++i) {   // stage h1[t-1] half (32KB)
                    const int g = i*512 + tid;
                    const int lb = g >> 6, kc = g & 63;
                    const f16* src = h1buf + sR*BH + (size_t)(bhalf*32 + lb)*H_ + ((kc ^ (lb & 7)) * 8);
                    *(half8*)(smem + 8192 + g*16) = *(const half8*)src;
                }
                __syncthreads();
                floatx4 acc0 = {0.f,0.f,0.f,0.f}, acc1 = {0.f,0.f,0.f,0.f};
                #pragma unroll
                for (int k = 0; k < 9; ++k) {
                    const int kt = kh*9 + k;
                    half8 a;
                    if (kt < 2) {
                        const int fg = kt*8 + quad*2;
                        float4 u = *(const float4*)(smem + ((size_t)lb_a*16 + (fg ^ sw_a))*16);
                        float4 v = *(const float4*)(smem + ((size_t)lb_a*16 + ((fg+1) ^ sw_a))*16);
                        a = (half8){(f16)u.x,(f16)u.y,(f16)u.z,(f16)u.w,
                                    (f16)v.x,(f16)v.y,(f16)v.z,(f16)v.w};
                    } else {
                        const int kc = (kt-2)*4 + quad;
                        a = *(const half8*)(smem + 8192 + ((size_t)lb_a*64 + (kc ^ sw_a))*16);
                    }
                    acc0 = MFMA16(a, wr[0][k], acc0);
                    acc1 = MFMA16(a, wr[1][k], acc1);
                }
                if (kh == 1) {
                    #pragma unroll
                    for (int r = 0; r < 4; ++r) {
                        RA[(gp*2+0)*512 + (mq*16 + quad*4 + r)*16 + col] = acc0[r];
                        RA[(gp*2+1)*512 + (mq*16 + quad*4 + r)*16 + col] = acc1[r];
                    }
                }
                __syncthreads();
                if (kh == 0) {
                    #pragma unroll
                    for (int r = 0; r < 4; ++r) {
                        const int i0 = (gp*2+0)*512 + (mq*16 + quad*4 + r)*16 + col;
                        const int i1 = (gp*2+1)*512 + (mq*16 + quad*4 + r)*16 + col;
                        RA[i0] += acc0[r];
                        RA[i1] += acc1[r];
                    }
                }
                __syncthreads();
                {   // pointwise, 512 elems = 32 b x 16 j
                    const float gi_ = RA[       tid] + bsr[0];
                    const float gf_ = RA[ 512 + tid] + bsr[1];
                    const float gg_ = RA[1024 + tid] + bsr[2];
                    const float go_ = RA[1536 + tid] + bsr[3];
                    const float i_ = sigmoidf_(gi_);
                    const float f_ = sigmoidf_(gf_);
                    const float g_ = tanhf_(gg_);
                    const float o_ = sigmoidf_(go_);
                    const float cn = f_ * CC[tid] + i_ * g_;
                    CC[tid] = cn;
                    const int b = bhalf*32 + (tid >> 4);
                    h1buf[sW*BH + (size_t)b*H_ + jt*16 + (tid & 15)] = (f16)(o_ * tanhf_(cn));
                }
            }
            gridbar(cnt, p);
        }
    } else if (wg < 128) {
        // ================= layer 2 =================
        const int v = wg - 64;
        const int jt = v & 31, bhalf = v >> 5;
        const int gp = w & 1, kq = w >> 1;
        half8 wr[2][8];
        #pragma unroll
        for (int gi = 0; gi < 2; ++gi)
            #pragma unroll
            for (int k = 0; k < 8; ++k) {
                const int g = gp*2 + gi, kt = kq*8 + k;
                wr[gi][k] = *(const half8*)(W2p + ((size_t)((g*32 + jt)*32 + kt)*64 + lane)*8);
            }
        float bsr[4];
        #pragma unroll
        for (int g = 0; g < 4; ++g) bsr[g] = bs2[g*512 + jt*16 + (tid & 15)];
        CC[tid] = 0.f;

        const int lb0 = col, lb1 = 16 + col;
        const int swz = col & 7;

        for (int p = 0; p < T_ + 2; ++p) {
            if (p >= 1 && p <= T_) {
                const int t2 = p - 1;
                const int sH1 = t2 & 1;
                const int sR  = (t2 + 1) & 1;
                const int sW  = t2 & 1;
                floatx4 acc00={0.f,0.f,0.f,0.f}, acc01={0.f,0.f,0.f,0.f};
                floatx4 acc10={0.f,0.f,0.f,0.f}, acc11={0.f,0.f,0.f,0.f};
                // ---- pass A: h1[t2] ----
                #pragma unroll
                for (int i = 0; i < 4; ++i) {
                    const int g = i*512 + tid;
                    const int lb = g >> 6, kc = g & 63;
                    const f16* src = h1buf + sH1*BH + (size_t)(bhalf*32 + lb)*H_ + ((kc ^ (lb & 7)) * 8);
                    *(half8*)(smem + 8192 + g*16) = *(const half8*)src;
                }
                __syncthreads();
                if (kq < 2) {
                    #pragma unroll
                    for (int k = 0; k < 8; ++k) {
                        const int kc = (kq*8 + k)*4 + quad;      // 0..63
                        half8 a0 = *(const half8*)(smem + 8192 + ((size_t)lb0*64 + (kc ^ swz))*16);
                        half8 a1 = *(const half8*)(smem + 8192 + ((size_t)lb1*64 + (kc ^ swz))*16);
                        acc00 = MFMA16(a0, wr[0][k], acc00);
                        acc10 = MFMA16(a0, wr[1][k], acc10);
                        acc01 = MFMA16(a1, wr[0][k], acc01);
                        acc11 = MFMA16(a1, wr[1][k], acc11);
                    }
                }
                __syncthreads();
                // ---- pass B: h2[t2-1] ----
                #pragma unroll
                for (int i = 0; i < 4; ++i) {
                    const int g = i*512 + tid;
                    const int lb = g >> 6, kc = g & 63;
                    const f16* src = h2buf + sR*BH + (size_t)(bhalf*32 + lb)*H_ + ((kc ^ (lb & 7)) * 8);
                    *(half8*)(smem + 8192 + g*16) = *(const half8*)src;
                }
                __syncthreads();
                if (kq >= 2) {
                    #pragma unroll
                    for (int k = 0; k < 8; ++k) {
                        const int kc = ((kq-2)*8 + k)*4 + quad;  // 0..63
                        half8 a0 = *(const half8*)(smem + 8192 + ((size_t)lb0*64 + (kc ^ swz))*16);
                        half8 a1 = *(const half8*)(smem + 8192 + ((size_t)lb1*64 + (kc ^ swz))*16);
                        acc00 = MFMA16(a0, wr[0][k], acc00);
                        acc10 = MFMA16(a0, wr[1][k], acc10);
                        acc01 = MFMA16(a1, wr[0][k], acc01);
                        acc11 = MFMA16(a1, wr[1][k], acc11);
                    }
                }
                // ---- 4-way kq reduction ----
                if (kq == 1 || kq == 3) {
                    float* R = (kq == 1) ? RA : RB;
                    #pragma unroll
                    for (int r = 0; r < 4; ++r) {
                        R[(gp*2+0)*512 + ( 0 + quad*4 + r)*16 + col] = acc00[r];
                        R[(gp*2+1)*512 + ( 0 + quad*4 + r)*16 + col] = acc10[r];
                        R[(gp*2+0)*512 + (16 + quad*4 + r)*16 + col] = acc01[r];
                        R[(gp*2+1)*512 + (16 + quad*4 + r)*16 + col] = acc11[r];
                    }
                }
                __syncthreads();
                if (kq == 0) {
                    #pragma unroll
                    for (int r = 0; r < 4; ++r) {
                        acc00[r] += RA[(gp*2+0)*512 + ( 0 + quad*4 + r)*16 + col];
                        acc10[r] += RA[(gp*2+1)*512 + ( 0 + quad*4 + r)*16 + col];
                        acc01[r] += RA[(gp*2+0)*512 + (16 + quad*4 + r)*16 + col];
                        acc11[r] += RA[(gp*2+1)*512 + (16 + quad*4 + r)*16 + col];
                    }
                } else if (kq == 2) {
                    #pragma unroll
                    for (int r = 0; r < 4; ++r) {
                        const int i00 = (gp*2+0)*512 + ( 0 + quad*4 + r)*16 + col;
                        const int i10 = (gp*2+1)*512 + ( 0 + quad*4 + r)*16 + col;
                        const int i01 = (gp*2+0)*512 + (16 + quad*4 + r)*16 + col;
                        const int i11 = (gp*2+1)*512 + (16 + quad*4 + r)*16 + col;
                        RB[i00] += acc00[r];
                        RB[i10] += acc10[r];
                        RB[i01] += acc01[r];
                        RB[i11] += acc11[r];
                    }
                }
                __syncthreads();
                if (kq == 0) {
                    #pragma unroll
                    for (int r = 0; r < 4; ++r) {
                        const int i00 = (gp*2+0)*512 + ( 0 + quad*4 + r)*16 + col;
                        const int i10 = (gp*2+1)*512 + ( 0 + quad*4 + r)*16 + col;
                        const int i01 = (gp*2+0)*512 + (16 + quad*4 + r)*16 + col;
                        const int i11 = (gp*2+1)*512 + (16 + quad*4 + r)*16 + col;
                        RA[i00] = acc00[r] + RB[i00];
                        RA[i10] = acc10[r] + RB[i10];
                        RA[i01] = acc01[r] + RB[i01];
                        RA[i11] = acc11[r] + RB[i11];
                    }
                }
                __syncthreads();
                {   // pointwise
                    const float gi_ = RA[       tid] + bsr[0];
                    const float gf_ = RA[ 512 + tid] + bsr[1];
                    const float gg_ = RA[1024 + tid] + bsr[2];
                    const float go_ = RA[1536 + tid] + bsr[3];
                    const float i_ = sigmoidf_(gi_);
                    const float f_ = sigmoidf_(gf_);
                    const float g_ = tanhf_(gg_);
                    const float o_ = sigmoidf_(go_);
                    const float cn = f_ * CC[tid] + i_ * g_;
                    CC[tid] = cn;
                    const int b = bhalf*32 + (tid >> 4);
                    h2buf[sW*BH + (size_t)b*H_ + jt*16 + (tid & 15)] = (f16)(o_ * tanhf_(cn));
                }
            }
            gridbar(cnt, p);
        }
    } else {
        // ================= head =================
        const int bhalf = wg - 128;
        const int nt = w & 3, kh = w >> 2;
        half8 wr[8];
        #pragma unroll
        for (int k = 0; k < 8; ++k) {
            const int kt = kh*8 + k;
            wr[k] = *(const half8*)(Wop + ((size_t)(nt*16 + kt)*64 + lane)*8);
        }
        const float boutr = bout[nt*16 + col];
        const int lb0 = col, lb1 = 16 + col;
        const int swz = col & 7;

        for (int p = 0; p < T_ + 2; ++p) {
            if (p >= 2) {
                const int t3 = p - 2;
                const int sH = t3 & 1;
                #pragma unroll
                for (int i = 0; i < 4; ++i) {
                    const int g = i*512 + tid;
                    const int lb = g >> 6, kc = g & 63;
                    const f16* src = h2buf + sH*BH + (size_t)(bhalf*32 + lb)*H_ + ((kc ^ (lb & 7)) * 8);
                    *(half8*)(smem + 8192 + g*16) = *(const half8*)src;
                }
                __syncthreads();
                floatx4 acc0 = {0.f,0.f,0.f,0.f}, acc1 = {0.f,0.f,0.f,0.f};
                #pragma unroll
                for (int k = 0; k < 8; ++k) {
                    const int kc = (kh*8 + k)*4 + quad;
                    half8 a0 = *(const half8*)(smem + 8192 + ((size_t)lb0*64 + (kc ^ swz))*16);
                    half8 a1 = *(const half8*)(smem + 8192 + ((size_t)lb1*64 + (kc ^ swz))*16);
                    acc0 = MFMA16(a0, wr[k], acc0);
                    acc1 = MFMA16(a1, wr[k], acc1);
                }
                if (kh == 1) {
                    #pragma unroll
                    for (int r = 0; r < 4; ++r) {
                        RA[(nt*2+0)*256 + (quad*4 + r)*16 + col] = acc0[r];
                        RA[(nt*2+1)*256 + (quad*4 + r)*16 + col] = acc1[r];
                    }
                }
                __syncthreads();
                if (kh == 0) {
                    #pragma unroll
                    for (int r = 0; r < 4; ++r) {
                        const float v0 = acc0[r] + RA[(nt*2+0)*256 + (quad*4 + r)*16 + col] + boutr;
                        const float v1 = acc1[r] + RA[(nt*2+1)*256 + (quad*4 + r)*16 + col] + boutr;
                        const int b0 = bhalf*32 +  0 + quad*4 + r;
                        const int b1 = bhalf*32 + 16 + quad*4 + r;
                        y[((size_t)b0*T_ + t3)*OUT_ + nt*16 + col] = v0;
                        y[((size_t)b1*T_ + t3)*OUT_ + nt*16 + col] = v1;
                    }
                }
            }
            gridbar(cnt, p);
        }
    }
}

// ---------------- launch ----------------
extern "C" void kernel_launch(void* const* d_in, const int* in_sizes, int n_in,
                              void* d_out, int out_size, void* d_ws, size_t ws_size,
                              hipStream_t stream) {
    const float* x    = (const float*)d_in[0];
    const float* Wih1 = (const float*)d_in[1];
    const float* Whh1 = (const float*)d_in[2];
    const float* bih1 = (const float*)d_in[3];
    const float* bhh1 = (const float*)d_in[4];
    const float* Wih2 = (const float*)d_in[5];
    const float* Whh2 = (const float*)d_in[6];
    const float* bih2 = (const float*)d_in[7];
    const float* bhh2 = (const float*)d_in[8];
    const float* Wout = (const float*)d_in[9];
    const float* bout = (const float*)d_in[10];
    float* y = (float*)d_out;

    char* ws = (char*)d_ws;
    f16*   W1p   = (f16*)(ws + 0);           // 2,359,296 B
    f16*   W2p   = (f16*)(ws + 2359296);     // 4,194,304 B
    f16*   Wop   = (f16*)(ws + 6553600);     //    65,536 B
    float* bs1   = (float*)(ws + 6619136);   //     8,192 B
    float* bs2   = (float*)(ws + 6627328);   //     8,192 B
    f16*   h1buf = (f16*)(ws + 6635520);     //   131,072 B
    f16*   h2buf = (f16*)(ws + 6766592);     //   131,072 B
    u32*   cnt   = (u32*)(ws + 6897664);     //       256 B

    // zero h-state slots + barrier counter
    hipMemsetAsync(ws + 6635520, 0, 262400, stream);

    pack_w1<<<4608, 256, 0, stream>>>(Wih1, Whh1, W1p);
    pack_w2<<<8192, 256, 0, stream>>>(Wih2, Whh2, W2p);
    pack_wo<<<128, 256, 0, stream>>>(Wout, Wop);
    bias_sum<<<8, 256, 0, stream>>>(bih1, bhh1, bih2, bhh2, bs1, bs2);

    lstm_persist<<<NWG, 512, 0, stream>>>(x, W1p, W2p, Wop, bs1, bs2, bout,
                                          h1buf, h2buf, y, cnt);
}

// Round 5
// 7516.114 us; speedup vs baseline: 1.5902x; 1.5902x over previous
//
#include <hip/hip_runtime.h>

#define B_   64
#define T_   1024
#define IN_  64
#define H_   512
#define OUT_ 64
#define BH   (64*512)   // elements per h slot
#define NWG  130

typedef _Float16 f16;
typedef _Float16 half8 __attribute__((ext_vector_type(8)));
typedef float    floatx4 __attribute__((ext_vector_type(4)));
typedef unsigned int u32;
typedef unsigned long long u64;

#define MFMA16(a,b,c) __builtin_amdgcn_mfma_f32_16x16x32_f16((a),(b),(c),0,0,0)

// LDS layout (92160 B total, 1 WG/CU)
#define XS_OFF   0        // 8KB: L1 x-stage; reused as h-publish buffer
#define H1S_OFF  8192     // 32KB: h1 stage (L1/L2); h2 stage (head)
#define H2S_OFF  40960    // 32KB: h2 stage (L2 only)
#define RA_OFF   73728    // 8KB reduction
#define RB_OFF   81920    // 8KB reduction
#define CC_OFF   90112    // 2KB c-state

__device__ __forceinline__ float sigmoidf_(float x) {
    return 1.0f / (1.0f + __expf(-x));
}
__device__ __forceinline__ float tanhf_(float x) {
    float ax = fabsf(x);
    float e  = __expf(-2.0f * ax);
    float t  = (1.0f - e) / (1.0f + e);
    return x >= 0.0f ? t : -t;
}

// Flags: agent-scope RMW (executes at coherence point) + agent poll — the
// combination empirically proven by R2's passing grid barrier.
__device__ __forceinline__ void wait_ge(u32* p, u32 v) {
    while (__hip_atomic_load(p, __ATOMIC_RELAXED, __HIP_MEMORY_SCOPE_AGENT) < v)
        __builtin_amdgcn_s_sleep(2);
}
__device__ __forceinline__ void flag_add(u32* p) {
    __hip_atomic_fetch_add(p, 1u, __ATOMIC_RELAXED, __HIP_MEMORY_SCOPE_AGENT);
}
// Data reads: SYSTEM-scope relaxed load -> sc0+sc1 (bypasses per-CU L1 AND
// per-XCD L2; reads the IF$ coherence point). sc1-only (agent) can hit a
// stale L1 line — slot addresses recycle every 4 steps.
__device__ __forceinline__ u64 aload8(const f16* p) {
    return __hip_atomic_load((const u64*)p, __ATOMIC_RELAXED, __HIP_MEMORY_SCOPE_SYSTEM);
}
// Data publish: RETURNING atomic exchange at system scope. Consuming the old
// value (asm sink) forces the returning form, whose vmcnt only retires after
// the IF$ round-trip -> the __syncthreads drain before flag_add genuinely
// orders data-at-IF$ before flag-at-IF$.
__device__ __forceinline__ void apub8(f16* p, u64 v) {
    u64 old = __hip_atomic_exchange((u64*)p, v, __ATOMIC_RELAXED, __HIP_MEMORY_SCOPE_SYSTEM);
    asm volatile("" : : "v"(old));
}

// ---------------- prep kernels (weights -> fp16 fragment-linear) ----------------
__global__ void pack_w1(const float* __restrict__ Wih, const float* __restrict__ Whh,
                        f16* __restrict__ Wp) {
    int idx = blockIdx.x * 256 + threadIdx.x;
    if (idx >= 4*32*18*512) return;
    int j    = idx & 7;
    int lane = (idx >> 3) & 63;
    int kt   = (idx >> 9) % 18;
    int r    = (idx >> 9) / 18;
    int jt   = r & 31;
    int g    = r >> 5;
    int n = g*512 + jt*16 + (lane & 15);
    int k = kt*32 + (lane >> 4)*8 + j;
    float v = (k < 64) ? Wih[n*64 + k] : Whh[n*512 + (k - 64)];
    Wp[idx] = (f16)v;
}

__global__ void pack_w2(const float* __restrict__ Wih, const float* __restrict__ Whh,
                        f16* __restrict__ Wp) {
    int idx = blockIdx.x * 256 + threadIdx.x;
    if (idx >= 4*32*32*512) return;
    int j    = idx & 7;
    int lane = (idx >> 3) & 63;
    int kt   = (idx >> 9) & 31;
    int r    = idx >> 14;
    int jt   = r & 31;
    int g    = r >> 5;
    int n = g*512 + jt*16 + (lane & 15);
    int k = kt*32 + (lane >> 4)*8 + j;
    float v = (k < 512) ? Wih[n*512 + k] : Whh[n*512 + (k - 512)];
    Wp[idx] = (f16)v;
}

__global__ void pack_wo(const float* __restrict__ Wout, f16* __restrict__ Wp) {
    int idx = blockIdx.x * 256 + threadIdx.x;
    if (idx >= 4*16*512) return;
    int j    = idx & 7;
    int lane = (idx >> 3) & 63;
    int kt   = (idx >> 9) & 15;
    int nt   = idx >> 13;
    int n = nt*16 + (lane & 15);
    int k = kt*32 + (lane >> 4)*8 + j;
    Wp[idx] = (f16)Wout[n*512 + k];
}

__global__ void bias_sum(const float* __restrict__ a1, const float* __restrict__ b1,
                         const float* __restrict__ a2, const float* __restrict__ b2,
                         float* __restrict__ s1, float* __restrict__ s2) {
    int i = blockIdx.x * 256 + threadIdx.x;
    if (i >= 2048) return;
    s1[i] = a1[i] + b1[i];
    s2[i] = a2[i] + b2[i];
}

// ---------------- persistent self-timed kernel ----------------
// WG 0..63:   layer1 (jt = wg&31, bhalf = wg>>5)
// WG 64..127: layer2 (v=wg-64: jt=v&31, bhalf=v>>5)
// WG 128..129: head (bhalf = wg-128)
// h buffers: 4 slots (slot = t&3). Cross-WG data via IF$-executed atomics;
// no cache-maintenance instructions anywhere.
__global__ __launch_bounds__(512, 1) void lstm_persist(
    const float* __restrict__ x,
    const f16*  __restrict__ W1p,
    const f16*  __restrict__ W2p,
    const f16*  __restrict__ Wop,
    const float* __restrict__ bs1,
    const float* __restrict__ bs2,
    const float* __restrict__ bout,
    f16*  __restrict__ h1buf,   // [4][64][512] fp16
    f16*  __restrict__ h2buf,   // [4][64][512] fp16
    float* __restrict__ y,
    u32*  __restrict__ arr1,    // [2][1024]
    u32*  __restrict__ arr2,    // [2][1024]
    u32*  __restrict__ arrH)    // [2][1024]
{
    __shared__ __align__(16) char smem[92160];
    float* RA = (float*)(smem + RA_OFF);
    float* RB = (float*)(smem + RB_OFF);
    float* CC = (float*)(smem + CC_OFF);

    const int wg   = blockIdx.x;
    const int tid  = threadIdx.x;
    const int lane = tid & 63;
    const int w    = tid >> 6;
    const int col  = lane & 15;
    const int quad = lane >> 4;

    if (wg < 64) {
        // ================= layer 1 =================
        const int jt = wg & 31, bhalf = wg >> 5;
        const int gp = w & 1, kh = (w >> 1) & 1, mq = w >> 2;
        half8 wr[2][9];
        #pragma unroll
        for (int gi = 0; gi < 2; ++gi)
            #pragma unroll
            for (int k = 0; k < 9; ++k) {
                const int g = gp*2 + gi, kt = kh*9 + k;
                wr[gi][k] = *(const half8*)(W1p + ((size_t)((g*32 + jt)*18 + kt)*64 + lane)*8);
            }
        float bsr[4];
        #pragma unroll
        for (int g = 0; g < 4; ++g) bsr[g] = bs1[g*512 + jt*16 + (tid & 15)];
        CC[tid] = 0.f;

        u32* a1 = arr1 + bhalf*1024;
        u32* a2 = arr2 + bhalf*1024;
        const int lb_a = mq*16 + col;
        const int sw_a = lb_a & 7;

        for (int t = 0; t < T_; ++t) {
            const int sR = (t + 3) & 3;   // h1[t-1] slot
            const int sW = t & 3;
            {   // stage x_t (plain loads, L2-cacheable; no flag dependency)
                const int lb = tid >> 4, kc4 = tid & 15;
                const float* src = x + ((size_t)(bhalf*32 + lb)*T_ + t)*(size_t)IN_ + ((kc4 ^ (lb & 7)) * 4);
                *(float4*)(smem + XS_OFF + tid*16) = *(const float4*)src;
            }
            if (tid == 0) {
                if (t >= 1) wait_ge(a1 + (t-1), 32u);   // full h1[t-1] published
                if (t >= 4) wait_ge(a2 + (t-4), 32u);   // L2 consumed h1[t-4] (slot reuse)
            }
            __syncthreads();
            // stage h1[t-1] bhalf-slice (32KB) via system-scope 8B atomic loads
            #pragma unroll
            for (int i = 0; i < 8; ++i) {
                const int g2 = i*512 + tid;
                const int lb = g2 >> 7, r = g2 & 127, q = r >> 1, hf = r & 1;
                u64 v = aload8(h1buf + (size_t)sR*BH + (size_t)(bhalf*32 + lb)*H_ + ((q ^ (lb & 7))*8 + hf*4));
                *(u64*)(smem + H1S_OFF + (size_t)(lb*64 + q)*16 + hf*8) = v;
            }
            __syncthreads();
            floatx4 acc0 = {0.f,0.f,0.f,0.f}, acc1 = {0.f,0.f,0.f,0.f};
            #pragma unroll
            for (int k = 0; k < 9; ++k) {
                const int kt = kh*9 + k;
                half8 a;
                if (kt < 2) {
                    const int fg = kt*8 + quad*2;
                    float4 u = *(const float4*)(smem + XS_OFF + ((size_t)lb_a*16 + (fg ^ sw_a))*16);
                    float4 v = *(const float4*)(smem + XS_OFF + ((size_t)lb_a*16 + ((fg+1) ^ sw_a))*16);
                    a = (half8){(f16)u.x,(f16)u.y,(f16)u.z,(f16)u.w,
                                (f16)v.x,(f16)v.y,(f16)v.z,(f16)v.w};
                } else {
                    const int kc = (kt-2)*4 + quad;
                    a = *(const half8*)(smem + H1S_OFF + ((size_t)lb_a*64 + (kc ^ sw_a))*16);
                }
                acc0 = MFMA16(a, wr[0][k], acc0);
                acc1 = MFMA16(a, wr[1][k], acc1);
            }
            if (kh == 1) {
                #pragma unroll
                for (int r = 0; r < 4; ++r) {
                    RA[(gp*2+0)*512 + (mq*16 + quad*4 + r)*16 + col] = acc0[r];
                    RA[(gp*2+1)*512 + (mq*16 + quad*4 + r)*16 + col] = acc1[r];
                }
            }
            __syncthreads();
            if (kh == 0) {
                #pragma unroll
                for (int r = 0; r < 4; ++r) {
                    RA[(gp*2+0)*512 + (mq*16 + quad*4 + r)*16 + col] += acc0[r];
                    RA[(gp*2+1)*512 + (mq*16 + quad*4 + r)*16 + col] += acc1[r];
                }
            }
            __syncthreads();
            {   // pointwise; h -> LDS publish buffer (XS area, x already consumed)
                const float gi_ = RA[       tid] + bsr[0];
                const float gf_ = RA[ 512 + tid] + bsr[1];
                const float gg_ = RA[1024 + tid] + bsr[2];
                const float go_ = RA[1536 + tid] + bsr[3];
                const float i_ = sigmoidf_(gi_);
                const float f_ = sigmoidf_(gf_);
                const float g_ = tanhf_(gg_);
                const float o_ = sigmoidf_(go_);
                const float cn = f_ * CC[tid] + i_ * g_;
                CC[tid] = cn;
                ((f16*)(smem + XS_OFF))[tid] = (f16)(o_ * tanhf_(cn));
            }
            __syncthreads();
            if (tid < 128) {   // publish slice via returning IF$-point exchanges
                const int b = tid >> 2, jq = tid & 3;
                u64 v = *(const u64*)(smem + XS_OFF + (size_t)(b*16 + jq*4)*2);
                apub8(h1buf + (size_t)sW*BH + (size_t)(bhalf*32 + b)*H_ + jt*16 + jq*4, v);
            }
            __syncthreads();   // drains publishing waves' vmcnt before flag
            if (tid == 0) flag_add(a1 + t);
        }
    } else if (wg < 128) {
        // ================= layer 2 =================
        const int v = wg - 64;
        const int jt = v & 31, bhalf = v >> 5;
        const int gp = w & 1, kq = w >> 1;
        half8 wr[2][8];
        #pragma unroll
        for (int gi = 0; gi < 2; ++gi)
            #pragma unroll
            for (int k = 0; k < 8; ++k) {
                const int g = gp*2 + gi, kt = kq*8 + k;
                wr[gi][k] = *(const half8*)(W2p + ((size_t)((g*32 + jt)*32 + kt)*64 + lane)*8);
            }
        float bsr[4];
        #pragma unroll
        for (int g = 0; g < 4; ++g) bsr[g] = bs2[g*512 + jt*16 + (tid & 15)];
        CC[tid] = 0.f;

        u32* a1 = arr1 + bhalf*1024;
        u32* a2 = arr2 + bhalf*1024;
        u32* aH = arrH + bhalf*1024;
        const int lb0 = col, lb1 = 16 + col;
        const int swz = col & 7;
        const char* rdbase = (kq < 2) ? (smem + H1S_OFF) : (smem + H2S_OFF);
        const int kq2 = kq & 1;

        for (int t2 = 0; t2 < T_; ++t2) {
            const int sH1 = t2 & 3;        // h1[t2] slot
            const int sR  = (t2 + 3) & 3;  // h2[t2-1] slot
            const int sW  = t2 & 3;
            if (tid == 0) {
                wait_ge(a1 + t2, 32u);                    // h1[t2] ready
                if (t2 >= 1) wait_ge(a2 + (t2-1), 32u);   // full h2[t2-1]
                if (t2 >= 4) wait_ge(aH + (t2-4), 1u);    // head consumed h2[t2-4]
            }
            __syncthreads();
            #pragma unroll
            for (int i = 0; i < 8; ++i) {   // stage h1[t2]
                const int g2 = i*512 + tid;
                const int lb = g2 >> 7, r = g2 & 127, q = r >> 1, hf = r & 1;
                u64 vv = aload8(h1buf + (size_t)sH1*BH + (size_t)(bhalf*32 + lb)*H_ + ((q ^ (lb & 7))*8 + hf*4));
                *(u64*)(smem + H1S_OFF + (size_t)(lb*64 + q)*16 + hf*8) = vv;
            }
            #pragma unroll
            for (int i = 0; i < 8; ++i) {   // stage h2[t2-1]
                const int g2 = i*512 + tid;
                const int lb = g2 >> 7, r = g2 & 127, q = r >> 1, hf = r & 1;
                u64 vv = aload8(h2buf + (size_t)sR*BH + (size_t)(bhalf*32 + lb)*H_ + ((q ^ (lb & 7))*8 + hf*4));
                *(u64*)(smem + H2S_OFF + (size_t)(lb*64 + q)*16 + hf*8) = vv;
            }
            __syncthreads();
            floatx4 acc00={0.f,0.f,0.f,0.f}, acc01={0.f,0.f,0.f,0.f};
            floatx4 acc10={0.f,0.f,0.f,0.f}, acc11={0.f,0.f,0.f,0.f};
            #pragma unroll
            for (int k = 0; k < 8; ++k) {
                const int kc = (kq2*8 + k)*4 + quad;      // 0..63 within region
                half8 a0 = *(const half8*)(rdbase + ((size_t)lb0*64 + (kc ^ swz))*16);
                half8 a1v = *(const half8*)(rdbase + ((size_t)lb1*64 + (kc ^ swz))*16);
                acc00 = MFMA16(a0,  wr[0][k], acc00);
                acc10 = MFMA16(a0,  wr[1][k], acc10);
                acc01 = MFMA16(a1v, wr[0][k], acc01);
                acc11 = MFMA16(a1v, wr[1][k], acc11);
            }
            // ---- 4-way kq reduction (3-phase) ----
            if (kq == 1 || kq == 3) {
                float* R = (kq == 1) ? RA : RB;
                #pragma unroll
                for (int r = 0; r < 4; ++r) {
                    R[(gp*2+0)*512 + ( 0 + quad*4 + r)*16 + col] = acc00[r];
                    R[(gp*2+1)*512 + ( 0 + quad*4 + r)*16 + col] = acc10[r];
                    R[(gp*2+0)*512 + (16 + quad*4 + r)*16 + col] = acc01[r];
                    R[(gp*2+1)*512 + (16 + quad*4 + r)*16 + col] = acc11[r];
                }
            }
            __syncthreads();
            if (kq == 0) {
                #pragma unroll
                for (int r = 0; r < 4; ++r) {
                    acc00[r] += RA[(gp*2+0)*512 + ( 0 + quad*4 + r)*16 + col];
                    acc10[r] += RA[(gp*2+1)*512 + ( 0 + quad*4 + r)*16 + col];
                    acc01[r] += RA[(gp*2+0)*512 + (16 + quad*4 + r)*16 + col];
                    acc11[r] += RA[(gp*2+1)*512 + (16 + quad*4 + r)*16 + col];
                }
            } else if (kq == 2) {
                #pragma unroll
                for (int r = 0; r < 4; ++r) {
                    const int i00 = (gp*2+0)*512 + ( 0 + quad*4 + r)*16 + col;
                    const int i10 = (gp*2+1)*512 + ( 0 + quad*4 + r)*16 + col;
                    const int i01 = (gp*2+0)*512 + (16 + quad*4 + r)*16 + col;
                    const int i11 = (gp*2+1)*512 + (16 + quad*4 + r)*16 + col;
                    RB[i00] += acc00[r];
                    RB[i10] += acc10[r];
                    RB[i01] += acc01[r];
                    RB[i11] += acc11[r];
                }
            }
            __syncthreads();
            if (kq == 0) {
                #pragma unroll
                for (int r = 0; r < 4; ++r) {
                    const int i00 = (gp*2+0)*512 + ( 0 + quad*4 + r)*16 + col;
                    const int i10 = (gp*2+1)*512 + ( 0 + quad*4 + r)*16 + col;
                    const int i01 = (gp*2+0)*512 + (16 + quad*4 + r)*16 + col;
                    const int i11 = (gp*2+1)*512 + (16 + quad*4 + r)*16 + col;
                    RA[i00] = acc00[r] + RB[i00];
                    RA[i10] = acc10[r] + RB[i10];
                    RA[i01] = acc01[r] + RB[i01];
                    RA[i11] = acc11[r] + RB[i11];
                }
            }
            __syncthreads();
            {   // pointwise
                const float gi_ = RA[       tid] + bsr[0];
                const float gf_ = RA[ 512 + tid] + bsr[1];
                const float gg_ = RA[1024 + tid] + bsr[2];
                const float go_ = RA[1536 + tid] + bsr[3];
                const float i_ = sigmoidf_(gi_);
                const float f_ = sigmoidf_(gf_);
                const float g_ = tanhf_(gg_);
                const float o_ = sigmoidf_(go_);
                const float cn = f_ * CC[tid] + i_ * g_;
                CC[tid] = cn;
                ((f16*)(smem + XS_OFF))[tid] = (f16)(o_ * tanhf_(cn));
            }
            __syncthreads();
            if (tid < 128) {
                const int b = tid >> 2, jq = tid & 3;
                u64 vv = *(const u64*)(smem + XS_OFF + (size_t)(b*16 + jq*4)*2);
                apub8(h2buf + (size_t)sW*BH + (size_t)(bhalf*32 + b)*H_ + jt*16 + jq*4, vv);
            }
            __syncthreads();
            if (tid == 0) flag_add(a2 + t2);
        }
    } else {
        // ================= head =================
        const int bhalf = wg - 128;
        const int nt = w & 3, kh = w >> 2;
        half8 wr[8];
        #pragma unroll
        for (int k = 0; k < 8; ++k) {
            const int kt = kh*8 + k;
            wr[k] = *(const half8*)(Wop + ((size_t)(nt*16 + kt)*64 + lane)*8);
        }
        const float boutr = bout[nt*16 + col];
        u32* a2 = arr2 + bhalf*1024;
        u32* aH = arrH + bhalf*1024;
        const int lb0 = col, lb1 = 16 + col;
        const int swz = col & 7;

        for (int t3 = 0; t3 < T_; ++t3) {
            const int sH = t3 & 3;
            if (tid == 0) wait_ge(a2 + t3, 32u);
            __syncthreads();
            #pragma unroll
            for (int i = 0; i < 8; ++i) {   // stage h2[t3]
                const int g2 = i*512 + tid;
                const int lb = g2 >> 7, r = g2 & 127, q = r >> 1, hf = r & 1;
                u64 vv = aload8(h2buf + (size_t)sH*BH + (size_t)(bhalf*32 + lb)*H_ + ((q ^ (lb & 7))*8 + hf*4));
                *(u64*)(smem + H1S_OFF + (size_t)(lb*64 + q)*16 + hf*8) = vv;
            }
            __syncthreads();   // staging loads drained -> safe to release back-pressure
            if (tid == 0) flag_add(aH + t3);
            floatx4 acc0 = {0.f,0.f,0.f,0.f}, acc1 = {0.f,0.f,0.f,0.f};
            #pragma unroll
            for (int k = 0; k < 8; ++k) {
                const int kc = (kh*8 + k)*4 + quad;
                half8 a0 = *(const half8*)(smem + H1S_OFF + ((size_t)lb0*64 + (kc ^ swz))*16);
                half8 a1v = *(const half8*)(smem + H1S_OFF + ((size_t)lb1*64 + (kc ^ swz))*16);
                acc0 = MFMA16(a0,  wr[k], acc0);
                acc1 = MFMA16(a1v, wr[k], acc1);
            }
            if (kh == 1) {
                #pragma unroll
                for (int r = 0; r < 4; ++r) {
                    RA[(nt*2+0)*256 + (quad*4 + r)*16 + col] = acc0[r];
                    RA[(nt*2+1)*256 + (quad*4 + r)*16 + col] = acc1[r];
                }
            }
            __syncthreads();
            if (kh == 0) {
                #pragma unroll
                for (int r = 0; r < 4; ++r) {
                    const float v0 = acc0[r] + RA[(nt*2+0)*256 + (quad*4 + r)*16 + col] + boutr;
                    const float v1 = acc1[r] + RA[(nt*2+1)*256 + (quad*4 + r)*16 + col] + boutr;
                    const int b0 = bhalf*32 +  0 + quad*4 + r;
                    const int b1 = bhalf*32 + 16 + quad*4 + r;
                    y[((size_t)b0*T_ + t3)*OUT_ + nt*16 + col] = v0;
                    y[((size_t)b1*T_ + t3)*OUT_ + nt*16 + col] = v1;
                }
            }
            __syncthreads();   // RA reuse next step
        }
    }
}

// ---------------- launch ----------------
extern "C" void kernel_launch(void* const* d_in, const int* in_sizes, int n_in,
                              void* d_out, int out_size, void* d_ws, size_t ws_size,
                              hipStream_t stream) {
    const float* x    = (const float*)d_in[0];
    const float* Wih1 = (const float*)d_in[1];
    const float* Whh1 = (const float*)d_in[2];
    const float* bih1 = (const float*)d_in[3];
    const float* bhh1 = (const float*)d_in[4];
    const float* Wih2 = (const float*)d_in[5];
    const float* Whh2 = (const float*)d_in[6];
    const float* bih2 = (const float*)d_in[7];
    const float* bhh2 = (const float*)d_in[8];
    const float* Wout = (const float*)d_in[9];
    const float* bout = (const float*)d_in[10];
    float* y = (float*)d_out;

    char* ws = (char*)d_ws;
    f16*   W1p   = (f16*)(ws + 0);           // 2,359,296 B
    f16*   W2p   = (f16*)(ws + 2359296);     // 4,194,304 B
    f16*   Wop   = (f16*)(ws + 6553600);     //    65,536 B
    float* bs1   = (float*)(ws + 6619136);   //     8,192 B
    float* bs2   = (float*)(ws + 6627328);   //     8,192 B
    f16*   h1buf = (f16*)(ws + 6635520);     // 4 slots = 262,144 B
    f16*   h2buf = (f16*)(ws + 6897664);     // 4 slots = 262,144 B
    u32*   arr1  = (u32*)(ws + 7159808);     //     8,192 B
    u32*   arr2  = (u32*)(ws + 7168000);     //     8,192 B
    u32*   arrH  = (u32*)(ws + 7176192);     //     8,192 B

    // zero h slots (t=-1 state lives in slot 3) + all arrival counters
    hipMemsetAsync(ws + 6635520, 0, 548864, stream);

    pack_w1<<<4608, 256, 0, stream>>>(Wih1, Whh1, W1p);
    pack_w2<<<8192, 256, 0, stream>>>(Wih2, Whh2, W2p);
    pack_wo<<<128, 256, 0, stream>>>(Wout, Wop);
    bias_sum<<<8, 256, 0, stream>>>(bih1, bhh1, bih2, bhh2, bs1, bs2);

    lstm_persist<<<NWG, 512, 0, stream>>>(x, W1p, W2p, Wop, bs1, bs2, bout,
                                          h1buf, h2buf, y, arr1, arr2, arrH);
}

// Round 6
// 5555.627 us; speedup vs baseline: 2.1513x; 1.3529x over previous
//
#include <hip/hip_runtime.h>

#define B_    64
#define T_    1024
#define IN_   64
#define H_    512
#define OUT_  64
#define SLOTS 8
#define BH    (64*512)   // elements per h slot
#define NWG   130

typedef _Float16 f16;
typedef _Float16 half8 __attribute__((ext_vector_type(8)));
typedef float    floatx4 __attribute__((ext_vector_type(4)));
typedef unsigned int u32;
typedef unsigned long long u64;

#define MFMA16(a,b,c) __builtin_amdgcn_mfma_f32_16x16x32_f16((a),(b),(c),0,0,0)

// LDS layout (108544 B, 1 WG/CU)
#define XS_OFF   0        // 8KB: L1 x-stage; also h-publish buffer (all stages)
#define H1S_OFF  8192     // 32KB: recurrent/h1 stage
#define H2S_OFF  40960    // 32KB: h2 stage (L2 pass B)
#define RED_OFF  73728    // 32KB: 4 kq-regions x 8KB partial-sum
#define CC_OFF   106496   // 2KB c-state

__device__ __forceinline__ float sigmoidf_(float x) {
    return 1.0f / (1.0f + __expf(-x));
}
__device__ __forceinline__ float tanhf_(float x) {
    float ax = fabsf(x);
    float e  = __expf(-2.0f * ax);
    float t  = (1.0f - e) / (1.0f + e);
    return x >= 0.0f ? t : -t;
}

// Flags: agent-scope RMW + agent-scope poll (proven R2/R5).
__device__ __forceinline__ void wait_ge(u32* p, u32 v) {
    while (__hip_atomic_load(p, __ATOMIC_RELAXED, __HIP_MEMORY_SCOPE_AGENT) < v)
        __builtin_amdgcn_s_sleep(1);
}
__device__ __forceinline__ void flag_add(u32* p) {
    __hip_atomic_fetch_add(p, 1u, __ATOMIC_RELAXED, __HIP_MEMORY_SCOPE_AGENT);
}
// Data reads: system-scope relaxed load (sc0+sc1, reads IF$ coherence point). Proven R5.
__device__ __forceinline__ u64 aload8(const f16* p) {
    return __hip_atomic_load((const u64*)p, __ATOMIC_RELAXED, __HIP_MEMORY_SCOPE_SYSTEM);
}
// Data publish: RETURNING system-scope exchange; vmcnt retires only after the
// IF$ round-trip, so the pre-flag __syncthreads orders data before flag. Proven R5.
__device__ __forceinline__ void apub8(f16* p, u64 v) {
    u64 old = __hip_atomic_exchange((u64*)p, v, __ATOMIC_RELAXED, __HIP_MEMORY_SCOPE_SYSTEM);
    asm volatile("" : : "v"(old));
}

// ---------------- prep kernels (weights -> fp16 fragment-linear) ----------------
__global__ void pack_w1(const float* __restrict__ Wih, const float* __restrict__ Whh,
                        f16* __restrict__ Wp) {
    int idx = blockIdx.x * 256 + threadIdx.x;
    if (idx >= 4*32*18*512) return;
    int j    = idx & 7;
    int lane = (idx >> 3) & 63;
    int kt   = (idx >> 9) % 18;
    int r    = (idx >> 9) / 18;
    int jt   = r & 31;
    int g    = r >> 5;
    int n = g*512 + jt*16 + (lane & 15);
    int k = kt*32 + (lane >> 4)*8 + j;
    float v = (k < 64) ? Wih[n*64 + k] : Whh[n*512 + (k - 64)];
    Wp[idx] = (f16)v;
}

__global__ void pack_w2(const float* __restrict__ Wih, const float* __restrict__ Whh,
                        f16* __restrict__ Wp) {
    int idx = blockIdx.x * 256 + threadIdx.x;
    if (idx >= 4*32*32*512) return;
    int j    = idx & 7;
    int lane = (idx >> 3) & 63;
    int kt   = (idx >> 9) & 31;
    int r    = idx >> 14;
    int jt   = r & 31;
    int g    = r >> 5;
    int n = g*512 + jt*16 + (lane & 15);
    int k = kt*32 + (lane >> 4)*8 + j;
    float v = (k < 512) ? Wih[n*512 + k] : Whh[n*512 + (k - 512)];
    Wp[idx] = (f16)v;
}

__global__ void pack_wo(const float* __restrict__ Wout, f16* __restrict__ Wp) {
    int idx = blockIdx.x * 256 + threadIdx.x;
    if (idx >= 4*16*512) return;
    int j    = idx & 7;
    int lane = (idx >> 3) & 63;
    int kt   = (idx >> 9) & 15;
    int nt   = idx >> 13;
    int n = nt*16 + (lane & 15);
    int k = kt*32 + (lane >> 4)*8 + j;
    Wp[idx] = (f16)Wout[n*512 + k];
}

__global__ void bias_sum(const float* __restrict__ a1, const float* __restrict__ b1,
                         const float* __restrict__ a2, const float* __restrict__ b2,
                         float* __restrict__ s1, float* __restrict__ s2) {
    int i = blockIdx.x * 256 + threadIdx.x;
    if (i >= 2048) return;
    s1[i] = a1[i] + b1[i];
    s2[i] = a2[i] + b2[i];
}

// ---------------- persistent self-timed kernel ----------------
// WG 0..63:   layer1 (jt = wg&31, bhalf = wg>>5); waves gp=w&1, kq=w>>1 (K-slice)
// WG 64..127: layer2 (v=wg-64: jt=v&31, bhalf=v>>5); same wave split
// WG 128..129: head (bhalf = wg-128)
// h buffers: 8 slots (slot = t&7).
__global__ __launch_bounds__(512, 1) void lstm_persist(
    const float* __restrict__ x,
    const f16*  __restrict__ W1p,
    const f16*  __restrict__ W2p,
    const f16*  __restrict__ Wop,
    const float* __restrict__ bs1,
    const float* __restrict__ bs2,
    const float* __restrict__ bout,
    f16*  __restrict__ h1buf,   // [8][64][512] fp16
    f16*  __restrict__ h2buf,   // [8][64][512] fp16
    float* __restrict__ y,
    u32*  __restrict__ arr1,    // [2][1024]
    u32*  __restrict__ arr2,    // [2][1024]
    u32*  __restrict__ arrH)    // [2][1024]
{
    __shared__ __align__(16) char smem[108544];
    float* RED = (float*)(smem + RED_OFF);
    float* CC  = (float*)(smem + CC_OFF);

    const int wg   = blockIdx.x;
    const int tid  = threadIdx.x;
    const int lane = tid & 63;
    const int w    = tid >> 6;
    const int col  = lane & 15;
    const int quad = lane >> 4;

    if (wg < 64) {
        // ================= layer 1 =================
        const int jt = wg & 31, bhalf = wg >> 5;
        const int gp = w & 1, kq = w >> 1;
        // weights: x-tile kt=kq (kq<2 only), h-tiles kt = 2 + kq*4 + k
        half8 wrx[2];
        half8 wrh[2][4];
        if (kq < 2) {
            #pragma unroll
            for (int gi = 0; gi < 2; ++gi)
                wrx[gi] = *(const half8*)(W1p + ((size_t)(((gp*2+gi)*32 + jt)*18 + kq)*64 + lane)*8);
        }
        #pragma unroll
        for (int gi = 0; gi < 2; ++gi)
            #pragma unroll
            for (int k = 0; k < 4; ++k) {
                const int kt = 2 + kq*4 + k;
                wrh[gi][k] = *(const half8*)(W1p + ((size_t)(((gp*2+gi)*32 + jt)*18 + kt)*64 + lane)*8);
            }
        float bsr[4];
        #pragma unroll
        for (int g = 0; g < 4; ++g) bsr[g] = bs1[g*512 + jt*16 + (tid & 15)];
        CC[tid] = 0.f;

        u32* a1 = arr1 + bhalf*1024;
        u32* a2 = arr2 + bhalf*1024;

        for (int t = 0; t < T_; ++t) {
            const int sR = (t + SLOTS - 1) & (SLOTS-1);
            const int sW = t & (SLOTS-1);
            {   // stage x_t (plain loads)
                const int lb = tid >> 4, kc4 = tid & 15;
                const float* src = x + ((size_t)(bhalf*32 + lb)*T_ + t)*(size_t)IN_ + ((kc4 ^ (lb & 7)) * 4);
                *(float4*)(smem + XS_OFF + tid*16) = *(const float4*)src;
            }
            if (tid == 0) {
                if (t >= 1)     wait_ge(a1 + (t-1), 32u);      // recurrence
                if (t >= SLOTS) wait_ge(a2 + (t-SLOTS), 32u);  // slot reuse backpressure
            }
            __syncthreads();
            #pragma unroll
            for (int i = 0; i < 8; ++i) {   // stage h1[t-1]
                const int g2 = i*512 + tid;
                const int lb = g2 >> 7, r = g2 & 127, q = r >> 1, hf = r & 1;
                u64 v = aload8(h1buf + (size_t)sR*BH + (size_t)(bhalf*32 + lb)*H_ + ((q ^ (lb & 7))*8 + hf*4));
                *(u64*)(smem + H1S_OFF + (size_t)(lb*64 + q)*16 + hf*8) = v;
            }
            __syncthreads();
            floatx4 acc[2][2] = {{{0.f,0.f,0.f,0.f},{0.f,0.f,0.f,0.f}},
                                 {{0.f,0.f,0.f,0.f},{0.f,0.f,0.f,0.f}}};
            #pragma unroll
            for (int m = 0; m < 2; ++m) {
                const int lb_a = m*16 + col, sw = lb_a & 7;
                if (kq < 2) {   // x-part: this kq's 32-col tile
                    const int fg = kq*8 + quad*2;
                    float4 u = *(const float4*)(smem + XS_OFF + ((size_t)lb_a*16 + (fg ^ sw))*16);
                    float4 v = *(const float4*)(smem + XS_OFF + ((size_t)lb_a*16 + ((fg+1) ^ sw))*16);
                    half8 a = (half8){(f16)u.x,(f16)u.y,(f16)u.z,(f16)u.w,
                                      (f16)v.x,(f16)v.y,(f16)v.z,(f16)v.w};
                    acc[0][m] = MFMA16(a, wrx[0], acc[0][m]);
                    acc[1][m] = MFMA16(a, wrx[1], acc[1][m]);
                }
                #pragma unroll
                for (int k = 0; k < 4; ++k) {
                    const int kc = kq*16 + k*4 + quad;
                    half8 a = *(const half8*)(smem + H1S_OFF + ((size_t)lb_a*64 + (kc ^ sw))*16);
                    acc[0][m] = MFMA16(a, wrh[0][k], acc[0][m]);
                    acc[1][m] = MFMA16(a, wrh[1][k], acc[1][m]);
                }
            }
            #pragma unroll
            for (int gi = 0; gi < 2; ++gi) {
                const int g = gp*2 + gi;
                #pragma unroll
                for (int m = 0; m < 2; ++m)
                    #pragma unroll
                    for (int r = 0; r < 4; ++r)
                        RED[kq*2048 + g*512 + (m*16 + quad*4 + r)*16 + col] = acc[gi][m][r];
            }
            __syncthreads();
            {   // 4-way kq sum + pointwise
                float gt[4];
                #pragma unroll
                for (int g = 0; g < 4; ++g)
                    gt[g] = RED[       g*512 + tid] + RED[2048 + g*512 + tid]
                          + RED[4096 + g*512 + tid] + RED[6144 + g*512 + tid] + bsr[g];
                const float i_ = sigmoidf_(gt[0]);
                const float f_ = sigmoidf_(gt[1]);
                const float g_ = tanhf_(gt[2]);
                const float o_ = sigmoidf_(gt[3]);
                const float cn = f_ * CC[tid] + i_ * g_;
                CC[tid] = cn;
                ((f16*)(smem + XS_OFF))[tid] = (f16)(o_ * tanhf_(cn));
            }
            __syncthreads();
            if (tid < 128) {   // publish 1KB slice via returning exchanges
                const int b = tid >> 2, jq = tid & 3;
                u64 v = *(const u64*)(smem + XS_OFF + (size_t)(b*16 + jq*4)*2);
                apub8(h1buf + (size_t)sW*BH + (size_t)(bhalf*32 + b)*H_ + jt*16 + jq*4, v);
            }
            __syncthreads();
            if (tid == 0) flag_add(a1 + t);
        }
    } else if (wg < 128) {
        // ================= layer 2 =================
        const int v = wg - 64;
        const int jt = v & 31, bhalf = v >> 5;
        const int gp = w & 1, kq = w >> 1;
        half8 wrA[2][4], wrB[2][4];
        #pragma unroll
        for (int gi = 0; gi < 2; ++gi)
            #pragma unroll
            for (int k = 0; k < 4; ++k) {
                const int ktA = kq*4 + k;        // h1 half (K 0..511)
                const int ktB = 16 + kq*4 + k;   // h2 half (K 512..1023)
                wrA[gi][k] = *(const half8*)(W2p + ((size_t)(((gp*2+gi)*32 + jt)*32 + ktA)*64 + lane)*8);
                wrB[gi][k] = *(const half8*)(W2p + ((size_t)(((gp*2+gi)*32 + jt)*32 + ktB)*64 + lane)*8);
            }
        float bsr[4];
        #pragma unroll
        for (int g = 0; g < 4; ++g) bsr[g] = bs2[g*512 + jt*16 + (tid & 15)];
        CC[tid] = 0.f;

        u32* a1 = arr1 + bhalf*1024;
        u32* a2 = arr2 + bhalf*1024;
        u32* aH = arrH + bhalf*1024;

        for (int t2 = 0; t2 < T_; ++t2) {
            const int sH1 = t2 & (SLOTS-1);
            const int sRd = (t2 + SLOTS - 1) & (SLOTS-1);
            const int sW  = t2 & (SLOTS-1);
            if (tid == 0) {
                wait_ge(a1 + t2, 32u);                             // h1[t2] ready
                if (t2 >= SLOTS) wait_ge(aH + (t2-SLOTS), 1u);     // head consumed h2[t2-8]
            }
            __syncthreads();
            #pragma unroll
            for (int i = 0; i < 8; ++i) {   // stage h1[t2]
                const int g2 = i*512 + tid;
                const int lb = g2 >> 7, r = g2 & 127, q = r >> 1, hf = r & 1;
                u64 vv = aload8(h1buf + (size_t)sH1*BH + (size_t)(bhalf*32 + lb)*H_ + ((q ^ (lb & 7))*8 + hf*4));
                *(u64*)(smem + H1S_OFF + (size_t)(lb*64 + q)*16 + hf*8) = vv;
            }
            __syncthreads();
            floatx4 acc[2][2] = {{{0.f,0.f,0.f,0.f},{0.f,0.f,0.f,0.f}},
                                 {{0.f,0.f,0.f,0.f},{0.f,0.f,0.f,0.f}}};
            // ---- pass A (h1 half) — hides the arr2 detect below ----
            #pragma unroll
            for (int m = 0; m < 2; ++m) {
                const int lb_a = m*16 + col, sw = lb_a & 7;
                #pragma unroll
                for (int k = 0; k < 4; ++k) {
                    const int kc = kq*16 + k*4 + quad;
                    half8 a = *(const half8*)(smem + H1S_OFF + ((size_t)lb_a*64 + (kc ^ sw))*16);
                    acc[0][m] = MFMA16(a, wrA[0][k], acc[0][m]);
                    acc[1][m] = MFMA16(a, wrA[1][k], acc[1][m]);
                }
            }
            if (tid == 0 && t2 >= 1) wait_ge(a2 + (t2-1), 32u);    // recurrence
            __syncthreads();
            #pragma unroll
            for (int i = 0; i < 8; ++i) {   // stage h2[t2-1]
                const int g2 = i*512 + tid;
                const int lb = g2 >> 7, r = g2 & 127, q = r >> 1, hf = r & 1;
                u64 vv = aload8(h2buf + (size_t)sRd*BH + (size_t)(bhalf*32 + lb)*H_ + ((q ^ (lb & 7))*8 + hf*4));
                *(u64*)(smem + H2S_OFF + (size_t)(lb*64 + q)*16 + hf*8) = vv;
            }
            __syncthreads();
            // ---- pass B (h2 half) ----
            #pragma unroll
            for (int m = 0; m < 2; ++m) {
                const int lb_a = m*16 + col, sw = lb_a & 7;
                #pragma unroll
                for (int k = 0; k < 4; ++k) {
                    const int kc = kq*16 + k*4 + quad;
                    half8 a = *(const half8*)(smem + H2S_OFF + ((size_t)lb_a*64 + (kc ^ sw))*16);
                    acc[0][m] = MFMA16(a, wrB[0][k], acc[0][m]);
                    acc[1][m] = MFMA16(a, wrB[1][k], acc[1][m]);
                }
            }
            #pragma unroll
            for (int gi = 0; gi < 2; ++gi) {
                const int g = gp*2 + gi;
                #pragma unroll
                for (int m = 0; m < 2; ++m)
                    #pragma unroll
                    for (int r = 0; r < 4; ++r)
                        RED[kq*2048 + g*512 + (m*16 + quad*4 + r)*16 + col] = acc[gi][m][r];
            }
            __syncthreads();
            {   // 4-way kq sum + pointwise
                float gt[4];
                #pragma unroll
                for (int g = 0; g < 4; ++g)
                    gt[g] = RED[       g*512 + tid] + RED[2048 + g*512 + tid]
                          + RED[4096 + g*512 + tid] + RED[6144 + g*512 + tid] + bsr[g];
                const float i_ = sigmoidf_(gt[0]);
                const float f_ = sigmoidf_(gt[1]);
                const float g_ = tanhf_(gt[2]);
                const float o_ = sigmoidf_(gt[3]);
                const float cn = f_ * CC[tid] + i_ * g_;
                CC[tid] = cn;
                ((f16*)(smem + XS_OFF))[tid] = (f16)(o_ * tanhf_(cn));
            }
            __syncthreads();
            if (tid < 128) {
                const int b = tid >> 2, jq = tid & 3;
                u64 vv = *(const u64*)(smem + XS_OFF + (size_t)(b*16 + jq*4)*2);
                apub8(h2buf + (size_t)sW*BH + (size_t)(bhalf*32 + b)*H_ + jt*16 + jq*4, vv);
            }
            __syncthreads();
            if (tid == 0) flag_add(a2 + t2);
        }
    } else {
        // ================= head =================
        const int bhalf = wg - 128;
        const int nt = w & 3, kh = w >> 2;
        half8 wr[8];
        #pragma unroll
        for (int k = 0; k < 8; ++k) {
            const int kt = kh*8 + k;
            wr[k] = *(const half8*)(Wop + ((size_t)(nt*16 + kt)*64 + lane)*8);
        }
        const float boutr = bout[nt*16 + col];
        u32* a2 = arr2 + bhalf*1024;
        u32* aH = arrH + bhalf*1024;
        const int lb0 = col, lb1 = 16 + col;
        const int swz = col & 7;

        for (int t3 = 0; t3 < T_; ++t3) {
            const int sH = t3 & (SLOTS-1);
            if (tid == 0) wait_ge(a2 + t3, 32u);
            __syncthreads();
            #pragma unroll
            for (int i = 0; i < 8; ++i) {   // stage h2[t3]
                const int g2 = i*512 + tid;
                const int lb = g2 >> 7, r = g2 & 127, q = r >> 1, hf = r & 1;
                u64 vv = aload8(h2buf + (size_t)sH*BH + (size_t)(bhalf*32 + lb)*H_ + ((q ^ (lb & 7))*8 + hf*4));
                *(u64*)(smem + H1S_OFF + (size_t)(lb*64 + q)*16 + hf*8) = vv;
            }
            __syncthreads();   // staging drained -> release back-pressure
            if (tid == 0) flag_add(aH + t3);
            floatx4 acc0 = {0.f,0.f,0.f,0.f}, acc1 = {0.f,0.f,0.f,0.f};
            #pragma unroll
            for (int k = 0; k < 8; ++k) {
                const int kc = (kh*8 + k)*4 + quad;
                half8 a0 = *(const half8*)(smem + H1S_OFF + ((size_t)lb0*64 + (kc ^ swz))*16);
                half8 a1v = *(const half8*)(smem + H1S_OFF + ((size_t)lb1*64 + (kc ^ swz))*16);
                acc0 = MFMA16(a0,  wr[k], acc0);
                acc1 = MFMA16(a1v, wr[k], acc1);
            }
            if (kh == 1) {
                #pragma unroll
                for (int r = 0; r < 4; ++r) {
                    RED[(nt*2+0)*256 + (quad*4 + r)*16 + col] = acc0[r];
                    RED[(nt*2+1)*256 + (quad*4 + r)*16 + col] = acc1[r];
                }
            }
            __syncthreads();
            if (kh == 0) {
                #pragma unroll
                for (int r = 0; r < 4; ++r) {
                    const float v0 = acc0[r] + RED[(nt*2+0)*256 + (quad*4 + r)*16 + col] + boutr;
                    const float v1 = acc1[r] + RED[(nt*2+1)*256 + (quad*4 + r)*16 + col] + boutr;
                    const int b0 = bhalf*32 +  0 + quad*4 + r;
                    const int b1 = bhalf*32 + 16 + quad*4 + r;
                    y[((size_t)b0*T_ + t3)*OUT_ + nt*16 + col] = v0;
                    y[((size_t)b1*T_ + t3)*OUT_ + nt*16 + col] = v1;
                }
            }
            __syncthreads();   // RED reuse next step
        }
    }
}

// ---------------- launch ----------------
extern "C" void kernel_launch(void* const* d_in, const int* in_sizes, int n_in,
                              void* d_out, int out_size, void* d_ws, size_t ws_size,
                              hipStream_t stream) {
    const float* x    = (const float*)d_in[0];
    const float* Wih1 = (const float*)d_in[1];
    const float* Whh1 = (const float*)d_in[2];
    const float* bih1 = (const float*)d_in[3];
    const float* bhh1 = (const float*)d_in[4];
    const float* Wih2 = (const float*)d_in[5];
    const float* Whh2 = (const float*)d_in[6];
    const float* bih2 = (const float*)d_in[7];
    const float* bhh2 = (const float*)d_in[8];
    const float* Wout = (const float*)d_in[9];
    const float* bout = (const float*)d_in[10];
    float* y = (float*)d_out;

    char* ws = (char*)d_ws;
    f16*   W1p   = (f16*)(ws + 0);           // 2,359,296 B
    f16*   W2p   = (f16*)(ws + 2359296);     // 4,194,304 B
    f16*   Wop   = (f16*)(ws + 6553600);     //    65,536 B
    float* bs1   = (float*)(ws + 6619136);   //     8,192 B
    float* bs2   = (float*)(ws + 6627328);   //     8,192 B
    f16*   h1buf = (f16*)(ws + 6635520);     // 8 slots = 524,288 B
    f16*   h2buf = (f16*)(ws + 7159808);     // 8 slots = 524,288 B
    u32*   arr1  = (u32*)(ws + 7684096);     //     8,192 B
    u32*   arr2  = (u32*)(ws + 7692288);     //     8,192 B
    u32*   arrH  = (u32*)(ws + 7700480);     //     8,192 B

    // zero h slots (t=-1 state lives in slot 7) + all arrival counters
    hipMemsetAsync(ws + 6635520, 0, 1073152, stream);

    pack_w1<<<4608, 256, 0, stream>>>(Wih1, Whh1, W1p);
    pack_w2<<<8192, 256, 0, stream>>>(Wih2, Whh2, W2p);
    pack_wo<<<128, 256, 0, stream>>>(Wout, Wop);
    bias_sum<<<8, 256, 0, stream>>>(bih1, bhh1, bih2, bhh2, bs1, bs2);

    lstm_persist<<<NWG, 512, 0, stream>>>(x, W1p, W2p, Wop, bs1, bs2, bout,
                                          h1buf, h2buf, y, arr1, arr2, arrH);
}